// Round 11
// baseline (5253.596 us; speedup 1.0000x reference)
//
#include <hip/hip_runtime.h>
#include <hip/hip_bf16.h>

// LSTM: B=64, D=32, H=512, T=1024. gates = [h,x] @ [W_hh;W_ih]^T + b_ih + b_hh
// Round 11: R10 + software-pipelined exchange. The 8 coherent 16B staging
// loads (and x loads) for step t+1 are issued IMMEDIATELY after step t's
// publish stores -> load flight + staleness rounds overlap the epilogue
// tail/projection work instead of sitting on the critical path. Tag-in-data
// (bit16 of lo plane, d0 & d3 of each packet, tag=(t>>1)&1 ring-2) validates
// as before; optimistic loads that race producers simply retry.
// No flags, no drains, ONE barrier/step. 128 blocks (4 groups x 32 slices),
// 256 thr (4 waves). W_hi VGPR, W_lo LDS frag-contiguous, h staged via LDS.

typedef unsigned short ushort_t;
typedef unsigned int   uint_t;
typedef unsigned long long u64_t;
typedef __attribute__((ext_vector_type(8))) short bf16x8;
typedef __attribute__((ext_vector_type(4))) float f32x4;
typedef __attribute__((ext_vector_type(4))) uint_t u32x4;

#define T_STEPS 1024
#define HID     512
#define KDIM    544   // 512 h + 32 x
#define NBLK    128   // 4 groups * 32 slices
#define NTHR    256

__device__ inline ushort_t f2bf(float x) {
    __hip_bfloat16 h = __float2bfloat16(x);
    return *(ushort_t*)&h;
}
__device__ inline float bf2f(ushort_t u) {
    __hip_bfloat16 h = *(__hip_bfloat16*)&u;
    return __bfloat162float(h);
}

__device__ inline f32x4 MFMA(bf16x8 a, bf16x8 b, f32x4 c) {
    return __builtin_amdgcn_mfma_f32_16x16x32_bf16(a, b, c, 0, 0, 0);
}

// coherent 16B load/store (L1+L2 bypass, meets at Infinity Cache)
__device__ inline u32x4 cld16(const void* p) {
    u32x4 v;
    asm volatile("global_load_dwordx4 %0, %1, off sc0 sc1"
                 : "=v"(v) : "v"(p) : "memory");
    return v;
}
__device__ inline void cst16(void* p, u32x4 v) {
    asm volatile("global_store_dwordx4 %0, %1, off sc0 sc1"
                 :: "v"(p), "v"(v) : "memory");
}
__device__ inline void waitvm0() {
    asm volatile("s_waitcnt vmcnt(0)" ::: "memory");
}

// is_tanh: tanh(v)=(1-e)/(1+e), e=2^(-2.885*v); sigmoid(v)=1/(1+e), e=2^(-1.4427*v)
__device__ inline float act_gate(float v, int is_tanh) {
    float vc = fminf(fmaxf(v, -43.f), 43.f);
    float kk = is_tanh ? -2.88539008f : -1.44269504f;
    float e  = __builtin_exp2f(vc * kk);
    float num = is_tanh ? (1.f - e) : 1.f;
    return num * __builtin_amdgcn_rcpf(1.f + e);
}

__device__ inline float sel4(int i, float a, float b, float c, float d) {
    return (i == 0) ? a : (i == 1) ? b : (i == 2) ? c : d;
}

// ---------- prep kernels ----------

__global__ void k_init(uint_t* hx32) {
    int i = blockIdx.x * 256 + threadIdx.x;      // grid 256x256 = 65536
    // init h ring: value ~0 (denormal bf16), tag bit16 = 1 (differs from tag 0
    // expected at t=1/t=2) -> no ABA with init data.
    hx32[i] = 0x00010000u;                       // 2*4*128*16 x 16B = 65536 u32
}

__global__ void k_wcat(const float* __restrict__ wih, const float* __restrict__ whh,
                       ushort_t* __restrict__ wh, ushort_t* __restrict__ wl) {
    int r = blockIdx.x;                          // 2048 gate rows
    for (int k = threadIdx.x; k < KDIM; k += 256) {
        float w = (k < 512) ? whh[r * 512 + k] : wih[r * 32 + (k - 512)];
        ushort_t hh = f2bf(w);
        ushort_t ll = f2bf(w - bf2f(hh));
        wh[r * KDIM + k] = hh;
        wl[r * KDIM + k] = ll;
    }
}

// input (B=64, D=32, T=1024) fp32 -> xbuf[t][b][d] bf16 hi/lo
__global__ void k_xbuf(const float* __restrict__ in,
                       ushort_t* __restrict__ xh, ushort_t* __restrict__ xl) {
    __shared__ float tile[64][65];
    int bp = blockIdx.x >> 4;                    // batch pair 0..31
    int tt = blockIdx.x & 15;                    // t tile 0..15
    int t0 = tt * 64;
    int wv = threadIdx.x >> 6, l = threadIdx.x & 63;
    for (int r = wv * 16; r < wv * 16 + 16; r++) {
        int b = bp * 2 + (r >> 5), d = r & 31;
        tile[r][l] = in[(b * 32 + d) * 1024 + t0 + l];
    }
    __syncthreads();
    for (int i = 0; i < 16; i++) {
        int tl = wv * 16 + i;
        float v = tile[l][tl];
        ushort_t hh = f2bf(v);
        ushort_t ll = f2bf(v - bf2f(hh));
        int o = (t0 + tl) * 2048 + bp * 64 + l;  // = t*64*32 + b*32 + d
        xh[o] = hh;
        xl[o] = ll;
    }
}

// out[b][t] = conv_b + sum_s part[(g*32+s)*16 + bl][t]   (b = g*16+bl)
__global__ void k_reduce(const float* __restrict__ part, float* __restrict__ out,
                         const float* __restrict__ cvb) {
    int b = blockIdx.x >> 2;                     // 0..63
    int t = (blockIdx.x & 3) * 256 + threadIdx.x;
    int g = b >> 4, bl = b & 15;
    const float* p = part + ((size_t)(g * 32 * 16 + bl)) * 1024 + t;
    float sum = 0.f;
    #pragma unroll
    for (int s = 0; s < 32; s++) sum += p[(size_t)s * 16 * 1024];
    out[b * 1024 + t] = sum + cvb[0];
}

// ---------- main recurrent kernel ----------

__global__ __launch_bounds__(NTHR, 1) void k_lstm(
    const ushort_t* __restrict__ wh, const ushort_t* __restrict__ wlo,
    const ushort_t* __restrict__ xh, const ushort_t* __restrict__ xl,
    char* hx,
    const float* __restrict__ bih, const float* __restrict__ bhh,
    const float* __restrict__ convw, float* __restrict__ part)
{
    const int tid = threadIdx.x;
    const int w   = tid >> 6;          // wave 0..3 (unit nibble)
    const int l   = tid & 63;
    const int g   = blockIdx.x >> 5;   // batch group 0..3
    const int s   = blockIdx.x & 31;   // hidden slice 0..31 (16 units each)
    const int n   = l & 15;            // B-tile row within wave
    const int q   = l >> 4;            // quad
    const int gtn = n >> 2;            // gate 0..3 (i,f,g,o)
    const int u   = n & 3;             // unit within wave
    const int j   = s * 16 + w * 4 + u;// hidden unit 0..511
    const int row = gtn * HID + j;     // gate row 0..2047
    const int b0  = g * 16;
    const int wg  = s * 4 + w;         // producing-wave id in group, 0..127
    const int rl16 = w * 16 + n;

    __shared__ ushort_t bloF[17 * 4 * 64 * 8]; // W_lo frag-contig (69.6 KB)
    __shared__ u64_t    hs[2][4096];           // staged h, dbuf (64 KB)
    __shared__ float    projsh[4][16][32];     // projection partials (8 KB)

    // stage W_lo fragment-contiguous: thread (w,l) writes frag (k, q=w, rl=l)
    #pragma unroll
    for (int k = 0; k < 17; k++) {
        int ww = l >> 4, nn = l & 15;
        int rowr = (nn >> 2) * HID + s * 16 + ww * 4 + (nn & 3);
        *(bf16x8*)&bloF[((k * 4 + w) * 64 + l) * 8] =
            *(const bf16x8*)(wlo + rowr * KDIM + k * 32 + w * 8);
    }

    // W_hi fragments in registers: 17 K-chunks
    bf16x8 Bh[17];
    #pragma unroll
    for (int c = 0; c < 17; c++)
        Bh[c] = *(const bf16x8*)(wh + row * KDIM + c * 32 + q * 8);

    const float bias = bih[row] + bhh[row];
    const float cw   = convw[j];
    float cst[4] = {0.f, 0.f, 0.f, 0.f};

    // staging mapping: 16B unit i = k*256+tid -> wg' = k*16+(tid>>4), m=tid&15
    // -> c = 2k + (hi4>>3), q = (hi4>>1)&3, d = hi4&1, n = m
    const int m16 = tid & 15;
    const int hi4 = tid >> 4;
    const int sq  = (hi4 >> 1) & 3, sd = hi4 & 1, sc0v = hi4 >> 3;

    __syncthreads();

    union frag { u64_t d[2]; bf16x8 v; };

    // persistent pipelined state: staged h packets + x fragments
    u32x4 hv[8];
    frag Ax, Lx;
    {   // initial issue for t=0 (slot 0; init data, no tag check at t=0)
        const char* srcB = hx + (size_t)g * 32768 + tid * 16;
        #pragma unroll
        for (int k = 0; k < 8; k++) hv[k] = cld16(srcB + k * 4096);
        int xo = (b0 + n) * 32 + q * 8;
        Ax.v = *(const bf16x8*)(xh + xo);
        Lx.v = *(const bf16x8*)(xl + xo);
    }

    for (int t = 0; t < T_STEPS; t++) {
        // ---- wait + validate the pre-issued loads ----
        const char* srcB = hx + (size_t)(((t & 1) * 4 + g)) * 32768 + tid * 16;
        waitvm0();
        if (t > 0) {
            const uint_t exp = ((uint_t)(((t - 1) >> 1) & 1)) << 16;
            for (;;) {
                bool ok = true;
                #pragma unroll
                for (int k = 0; k < 8; k++) {
                    if (((hv[k][0] & 0x10000u) != exp) ||
                        ((hv[k][3] & 0x10000u) != exp)) {
                        hv[k] = cld16(srcB + k * 4096);
                        ok = false;
                    }
                }
                if (ok) break;
                waitvm0();
            }
        }
        // deinterleave dwords (hi,lo)x4 units -> hi x4, lo x4; into LDS dbuf
        {
            const int buf = t & 1;
            #pragma unroll
            for (int k = 0; k < 8; k++) {
                uint_t I0 = hv[k][0], I1 = hv[k][1];
                uint_t I2 = hv[k][2], I3 = hv[k][3];
                uint_t hA = __builtin_amdgcn_perm(I1, I0, 0x05040100u);
                uint_t hB = __builtin_amdgcn_perm(I3, I2, 0x05040100u);
                uint_t lA = __builtin_amdgcn_perm(I1, I0, 0x07060302u);
                uint_t lB = __builtin_amdgcn_perm(I3, I2, 0x07060302u);
                int c  = 2 * k + sc0v;
                int li = ((c * 4 + sq) * 16 + m16) * 2 + sd;
                hs[buf][li]        = (u64_t)hA | ((u64_t)hB << 32);
                hs[buf][li + 2048] = (u64_t)lA | ((u64_t)lB << 32);
            }
        }
        __syncthreads();   // the only per-step barrier

        // fragments from LDS: contiguous 16B b128 reads
        const int buf = t & 1;
        f32x4 a0 = {0,0,0,0}, a1 = {0,0,0,0}, a2 = {0,0,0,0},
              a3 = {0,0,0,0}, a4 = {0,0,0,0}, a5 = {0,0,0,0};
        #pragma unroll
        for (int c = 0; c < 16; c++) {
            frag Ah, Al;
            int li = ((c * 4 + q) * 16 + n) * 2;
            Ah.v = *(const bf16x8*)&hs[buf][li];
            Al.v = *(const bf16x8*)&hs[buf][li + 2048];
            bf16x8 bl_ = *(const bf16x8*)&bloF[((c * 4 + q) * 64 + rl16) * 8];
            if (c & 1) {
                a1 = MFMA(Ah.v, Bh[c], a1);
                a3 = MFMA(Ah.v, bl_,   a3);
                a5 = MFMA(Al.v, Bh[c], a5);
            } else {
                a0 = MFMA(Ah.v, Bh[c], a0);
                a2 = MFMA(Ah.v, bl_,   a2);
                a4 = MFMA(Al.v, Bh[c], a4);
            }
        }
        {   // x chunk (c=16)
            bf16x8 bl_ = *(const bf16x8*)&bloF[((16 * 4 + q) * 64 + rl16) * 8];
            a0 = MFMA(Ax.v, Bh[16], a0);
            a2 = MFMA(Ax.v, bl_,    a2);
            a4 = MFMA(Lx.v, Bh[16], a4);
        }
        f32x4 D = (a0 + a1) + (a2 + a3) + (a4 + a5);

        // epilogue: lane holds gate row n for batches m=q*4+r.
        // pack (hi,lo)x4 units into one 16B packet per r, tag d0 & d3.
        char* dstB = hx + (size_t)((((t + 1) & 1) * 4 + g) * 128 + wg) * 256;
        const uint_t tag32 = ((uint_t)((t >> 1) & 1)) << 16;
        float pr[4];
        #pragma unroll
        for (int r = 0; r < 4; r++) {
            float v   = D[r] + bias;
            float act = act_gate(v, gtn == 2);
            float v4  = __shfl_xor(act, 4);
            float v8  = __shfl_xor(act, 8);
            float v12 = __shfl_xor(v4, 8);
            // gate G lives at arr[gtn ^ G]; arr = {act, v4, v8, v12}
            float iv = sel4(gtn,     act, v4, v8, v12);
            float fv = sel4(gtn ^ 1, act, v4, v8, v12);
            float gv = sel4(gtn ^ 2, act, v4, v8, v12);
            float ov = sel4(gtn ^ 3, act, v4, v8, v12);
            float cc = fv * cst[r] + iv * gv;
            cst[r] = cc;
            float th = act_gate(cc, 1);
            float h  = ov * th;
            pr[r] = cw * h;
            ushort_t hb = f2bf(h);
            uint_t hvp = (uint_t)hb;
            uint_t lvp = (uint_t)f2bf(h - bf2f(hb));
            uint_t ivp = hvp | (lvp << 16);                 // (hi,lo) unit u
            uint_t ip1 = (uint_t)__shfl_xor((int)ivp, 1);   // unit u^1
            uint_t bl2 = (uint_t)__shfl_xor((int)ivp, 2);   // unit u^2
            uint_t bh2 = (uint_t)__shfl_xor((int)ip1, 2);   // unit u^3
            if (n == 0) {
                u32x4 pkt;
                pkt[0] = (ivp & ~0x10000u) | tag32;
                pkt[1] = ip1;
                pkt[2] = bl2;
                pkt[3] = (bh2 & ~0x10000u) | tag32;
                cst16(dstB + (q * 4 + r) * 16, pkt);
            }
        }
        // NO drain, NO flag: tagged data IS the publication.

        // ---- EARLY ISSUE of next step's h + x loads (overlaps flight with
        // projection work and the other producers' publishes) ----
        if (t + 1 < T_STEPS) {
            const char* nsrc = hx +
                (size_t)((((t + 1) & 1) * 4 + g)) * 32768 + tid * 16;
            #pragma unroll
            for (int k = 0; k < 8; k++) hv[k] = cld16(nsrc + k * 4096);
            int xo = ((t + 1) * 64 + b0 + n) * 32 + q * 8;
            Ax.v = *(const bf16x8*)(xh + xo);
            Lx.v = *(const bf16x8*)(xl + xo);
        }

        // projection partial (off critical path)
        #pragma unroll
        for (int r = 0; r < 4; r++) {
            pr[r] += __shfl_xor(pr[r], 1);
            pr[r] += __shfl_xor(pr[r], 2);
            if (n == 0) projsh[w][q * 4 + r][t & 31] = pr[r];
        }
        if ((t & 31) == 31) {
            __syncthreads();
            float* dpt = part + (size_t)((g * 32 + s) * 16) * 1024 + (t - 31);
            for (int i = tid; i < 512; i += NTHR) {
                int b = i >> 5, tl = i & 31;
                float v = (projsh[0][b][tl] + projsh[1][b][tl]) +
                          (projsh[2][b][tl] + projsh[3][b][tl]);
                __builtin_nontemporal_store(v, dpt + (size_t)b * 1024 + tl);
            }
            __syncthreads();
        }
    }
}

extern "C" void kernel_launch(void* const* d_in, const int* in_sizes, int n_in,
                              void* d_out, int out_size, void* d_ws, size_t ws_size,
                              hipStream_t stream) {
    const float* in  = (const float*)d_in[0];
    const float* Wih = (const float*)d_in[1];
    const float* Whh = (const float*)d_in[2];
    const float* bih = (const float*)d_in[3];
    const float* bhh = (const float*)d_in[4];
    const float* cvw = (const float*)d_in[5];
    const float* cvb = (const float*)d_in[6];
    float* out = (float*)d_out;

    char* ws = (char*)d_ws;
    ushort_t* wh  = (ushort_t*)ws; ws += (size_t)2048 * KDIM * 2;      // 2,228,224
    ushort_t* wl  = (ushort_t*)ws; ws += (size_t)2048 * KDIM * 2;
    ushort_t* xh  = (ushort_t*)ws; ws += (size_t)1024 * 64 * 32 * 2;   // 4,194,304
    ushort_t* xl  = (ushort_t*)ws; ws += (size_t)1024 * 64 * 32 * 2;
    char*     hx  = ws;            ws += (size_t)2 * 4 * 128 * 16 * 16;// 262,144
    float*    pp  = (float*)ws;    ws += (size_t)128 * 16 * 1024 * 4;  // 8,388,608
    // total ~21.5 MB of ws

    k_init<<<256, 256, 0, stream>>>((uint_t*)hx);
    k_wcat<<<2048, 256, 0, stream>>>(Wih, Whh, wh, wl);
    k_xbuf<<<512, 256, 0, stream>>>(in, xh, xl);
    k_lstm<<<NBLK, NTHR, 0, stream>>>(wh, wl, xh, xl, hx,
                                      bih, bhh, cvw, pp);
    k_reduce<<<256, 256, 0, stream>>>(pp, out, cvb);
}

// Round 12
// 4114.191 us; speedup vs baseline: 1.2769x; 1.2769x over previous
//
#include <hip/hip_runtime.h>
#include <hip/hip_bf16.h>

// LSTM: B=64, D=32, H=512, T=1024. gates = [h,x] @ [W_hh;W_ih]^T + b_ih + b_hh
// Round 12: revert to R10 (best: 4.14 ms) + retry backoff.
//  - data-as-flag h exchange: 16B packets (4 units x (hi,lo)), tag bit16 in
//    d0 & d3, tag=(t>>1)&1 ring-2 (ABA-safe). Coherent dwordx4 sc0 sc1.
//  - staging loads issued at step top (NOT early — R11 showed early issue
//    costs a guaranteed-stale first round, +1.1us/step).
//  - s_sleep(1) backoff between retry rounds (fabric decongestion).
//  - projection partials flushed every 64 steps (projsh 16 KB).
// No flags, no drains, ONE barrier/step. 128 blocks (4 groups x 32 slices),
// 256 thr (4 waves). W_hi VGPR, W_lo LDS frag-contiguous, h staged via LDS.

typedef unsigned short ushort_t;
typedef unsigned int   uint_t;
typedef unsigned long long u64_t;
typedef __attribute__((ext_vector_type(8))) short bf16x8;
typedef __attribute__((ext_vector_type(4))) float f32x4;
typedef __attribute__((ext_vector_type(4))) uint_t u32x4;

#define T_STEPS 1024
#define HID     512
#define KDIM    544   // 512 h + 32 x
#define NBLK    128   // 4 groups * 32 slices
#define NTHR    256

__device__ inline ushort_t f2bf(float x) {
    __hip_bfloat16 h = __float2bfloat16(x);
    return *(ushort_t*)&h;
}
__device__ inline float bf2f(ushort_t u) {
    __hip_bfloat16 h = *(__hip_bfloat16*)&u;
    return __bfloat162float(h);
}

__device__ inline f32x4 MFMA(bf16x8 a, bf16x8 b, f32x4 c) {
    return __builtin_amdgcn_mfma_f32_16x16x32_bf16(a, b, c, 0, 0, 0);
}

// coherent 16B load/store (L1+L2 bypass, meets at Infinity Cache)
__device__ inline u32x4 cld16(const void* p) {
    u32x4 v;
    asm volatile("global_load_dwordx4 %0, %1, off sc0 sc1"
                 : "=v"(v) : "v"(p) : "memory");
    return v;
}
__device__ inline void cst16(void* p, u32x4 v) {
    asm volatile("global_store_dwordx4 %0, %1, off sc0 sc1"
                 :: "v"(p), "v"(v) : "memory");
}
__device__ inline void waitvm0() {
    asm volatile("s_waitcnt vmcnt(0)" ::: "memory");
}

// is_tanh: tanh(v)=(1-e)/(1+e), e=2^(-2.885*v); sigmoid(v)=1/(1+e), e=2^(-1.4427*v)
__device__ inline float act_gate(float v, int is_tanh) {
    float vc = fminf(fmaxf(v, -43.f), 43.f);
    float kk = is_tanh ? -2.88539008f : -1.44269504f;
    float e  = __builtin_exp2f(vc * kk);
    float num = is_tanh ? (1.f - e) : 1.f;
    return num * __builtin_amdgcn_rcpf(1.f + e);
}

__device__ inline float sel4(int i, float a, float b, float c, float d) {
    return (i == 0) ? a : (i == 1) ? b : (i == 2) ? c : d;
}

// ---------- prep kernels ----------

__global__ void k_init(uint_t* hx32) {
    int i = blockIdx.x * 256 + threadIdx.x;      // grid 256x256 = 65536
    // init h ring: value ~0 (denormal bf16), tag bit16 = 1 (differs from tag 0
    // expected at t=1/t=2) -> no ABA with init data.
    hx32[i] = 0x00010000u;                       // 2*4*128*16 x 16B = 65536 u32
}

__global__ void k_wcat(const float* __restrict__ wih, const float* __restrict__ whh,
                       ushort_t* __restrict__ wh, ushort_t* __restrict__ wl) {
    int r = blockIdx.x;                          // 2048 gate rows
    for (int k = threadIdx.x; k < KDIM; k += 256) {
        float w = (k < 512) ? whh[r * 512 + k] : wih[r * 32 + (k - 512)];
        ushort_t hh = f2bf(w);
        ushort_t ll = f2bf(w - bf2f(hh));
        wh[r * KDIM + k] = hh;
        wl[r * KDIM + k] = ll;
    }
}

// input (B=64, D=32, T=1024) fp32 -> xbuf[t][b][d] bf16 hi/lo
__global__ void k_xbuf(const float* __restrict__ in,
                       ushort_t* __restrict__ xh, ushort_t* __restrict__ xl) {
    __shared__ float tile[64][65];
    int bp = blockIdx.x >> 4;                    // batch pair 0..31
    int tt = blockIdx.x & 15;                    // t tile 0..15
    int t0 = tt * 64;
    int wv = threadIdx.x >> 6, l = threadIdx.x & 63;
    for (int r = wv * 16; r < wv * 16 + 16; r++) {
        int b = bp * 2 + (r >> 5), d = r & 31;
        tile[r][l] = in[(b * 32 + d) * 1024 + t0 + l];
    }
    __syncthreads();
    for (int i = 0; i < 16; i++) {
        int tl = wv * 16 + i;
        float v = tile[l][tl];
        ushort_t hh = f2bf(v);
        ushort_t ll = f2bf(v - bf2f(hh));
        int o = (t0 + tl) * 2048 + bp * 64 + l;  // = t*64*32 + b*32 + d
        xh[o] = hh;
        xl[o] = ll;
    }
}

// out[b][t] = conv_b + sum_s part[(g*32+s)*16 + bl][t]   (b = g*16+bl)
__global__ void k_reduce(const float* __restrict__ part, float* __restrict__ out,
                         const float* __restrict__ cvb) {
    int b = blockIdx.x >> 2;                     // 0..63
    int t = (blockIdx.x & 3) * 256 + threadIdx.x;
    int g = b >> 4, bl = b & 15;
    const float* p = part + ((size_t)(g * 32 * 16 + bl)) * 1024 + t;
    float sum = 0.f;
    #pragma unroll
    for (int s = 0; s < 32; s++) sum += p[(size_t)s * 16 * 1024];
    out[b * 1024 + t] = sum + cvb[0];
}

// ---------- main recurrent kernel ----------

__global__ __launch_bounds__(NTHR, 1) void k_lstm(
    const ushort_t* __restrict__ wh, const ushort_t* __restrict__ wlo,
    const ushort_t* __restrict__ xh, const ushort_t* __restrict__ xl,
    char* hx,
    const float* __restrict__ bih, const float* __restrict__ bhh,
    const float* __restrict__ convw, float* __restrict__ part)
{
    const int tid = threadIdx.x;
    const int w   = tid >> 6;          // wave 0..3 (unit nibble)
    const int l   = tid & 63;
    const int g   = blockIdx.x >> 5;   // batch group 0..3
    const int s   = blockIdx.x & 31;   // hidden slice 0..31 (16 units each)
    const int n   = l & 15;            // B-tile row within wave
    const int q   = l >> 4;            // quad
    const int gtn = n >> 2;            // gate 0..3 (i,f,g,o)
    const int u   = n & 3;             // unit within wave
    const int j   = s * 16 + w * 4 + u;// hidden unit 0..511
    const int row = gtn * HID + j;     // gate row 0..2047
    const int b0  = g * 16;
    const int wg  = s * 4 + w;         // producing-wave id in group, 0..127
    const int rl16 = w * 16 + n;

    __shared__ ushort_t bloF[17 * 4 * 64 * 8]; // W_lo frag-contig (69.6 KB)
    __shared__ u64_t    hs[2][4096];           // staged h, dbuf (64 KB)
    __shared__ float    projsh[4][16][64];     // projection partials (16 KB)

    // stage W_lo fragment-contiguous: thread (w,l) writes frag (k, q=w, rl=l)
    #pragma unroll
    for (int k = 0; k < 17; k++) {
        int ww = l >> 4, nn = l & 15;
        int rowr = (nn >> 2) * HID + s * 16 + ww * 4 + (nn & 3);
        *(bf16x8*)&bloF[((k * 4 + w) * 64 + l) * 8] =
            *(const bf16x8*)(wlo + rowr * KDIM + k * 32 + w * 8);
    }

    // W_hi fragments in registers: 17 K-chunks
    bf16x8 Bh[17];
    #pragma unroll
    for (int c = 0; c < 17; c++)
        Bh[c] = *(const bf16x8*)(wh + row * KDIM + c * 32 + q * 8);

    const float bias = bih[row] + bhh[row];
    const float cw   = convw[j];
    float cst[4] = {0.f, 0.f, 0.f, 0.f};

    // staging mapping: 16B unit i = k*256+tid -> wg' = k*16+(tid>>4), m=tid&15
    // -> c = 2k + (hi4>>3), q = (hi4>>1)&3, d = hi4&1, n = m
    const int m16 = tid & 15;
    const int hi4 = tid >> 4;
    const int sq  = (hi4 >> 1) & 3, sd = hi4 & 1, sc0v = hi4 >> 3;

    __syncthreads();

    union frag { u64_t d[2]; bf16x8 v; };

    for (int t = 0; t < T_STEPS; t++) {
        frag Ax, Lx;
        // x fragment (no recurrence dependence)
        {
            int xo = (t * 64 + b0 + n) * 32 + q * 8;
            Ax.v = *(const bf16x8*)(xh + xo);
            Lx.v = *(const bf16x8*)(xl + xo);
        }

        // ---- stage + poll-on-data: 8 coherent 16B loads, tag bit16 ----
        const char* srcB = hx + (size_t)(((t & 1) * 4 + g)) * 32768 + tid * 16;
        u32x4 hv[8];
        #pragma unroll
        for (int k = 0; k < 8; k++) hv[k] = cld16(srcB + k * 4096);
        waitvm0();
        if (t > 0) {
            const uint_t exp = ((uint_t)(((t - 1) >> 1) & 1)) << 16;
            for (;;) {
                bool ok = true;
                #pragma unroll
                for (int k = 0; k < 8; k++) {
                    if (((hv[k][0] & 0x10000u) != exp) ||
                        ((hv[k][3] & 0x10000u) != exp)) {
                        hv[k] = cld16(srcB + k * 4096);
                        ok = false;
                    }
                }
                if (ok) break;
                __builtin_amdgcn_s_sleep(1);   // backoff: decongest fabric
                waitvm0();
            }
        }
        // deinterleave dwords (hi,lo)x4 units -> hi x4, lo x4; into LDS dbuf
        {
            const int buf = t & 1;
            #pragma unroll
            for (int k = 0; k < 8; k++) {
                uint_t I0 = hv[k][0], I1 = hv[k][1];
                uint_t I2 = hv[k][2], I3 = hv[k][3];
                uint_t hA = __builtin_amdgcn_perm(I1, I0, 0x05040100u);
                uint_t hB = __builtin_amdgcn_perm(I3, I2, 0x05040100u);
                uint_t lA = __builtin_amdgcn_perm(I1, I0, 0x07060302u);
                uint_t lB = __builtin_amdgcn_perm(I3, I2, 0x07060302u);
                int c  = 2 * k + sc0v;
                int li = ((c * 4 + sq) * 16 + m16) * 2 + sd;
                hs[buf][li]        = (u64_t)hA | ((u64_t)hB << 32);
                hs[buf][li + 2048] = (u64_t)lA | ((u64_t)lB << 32);
            }
        }
        __syncthreads();   // the only per-step barrier

        // fragments from LDS: contiguous 16B b128 reads
        const int buf = t & 1;
        f32x4 a0 = {0,0,0,0}, a1 = {0,0,0,0}, a2 = {0,0,0,0},
              a3 = {0,0,0,0}, a4 = {0,0,0,0}, a5 = {0,0,0,0};
        #pragma unroll
        for (int c = 0; c < 16; c++) {
            frag Ah, Al;
            int li = ((c * 4 + q) * 16 + n) * 2;
            Ah.v = *(const bf16x8*)&hs[buf][li];
            Al.v = *(const bf16x8*)&hs[buf][li + 2048];
            bf16x8 bl_ = *(const bf16x8*)&bloF[((c * 4 + q) * 64 + rl16) * 8];
            if (c & 1) {
                a1 = MFMA(Ah.v, Bh[c], a1);
                a3 = MFMA(Ah.v, bl_,   a3);
                a5 = MFMA(Al.v, Bh[c], a5);
            } else {
                a0 = MFMA(Ah.v, Bh[c], a0);
                a2 = MFMA(Ah.v, bl_,   a2);
                a4 = MFMA(Al.v, Bh[c], a4);
            }
        }
        {   // x chunk (c=16)
            bf16x8 bl_ = *(const bf16x8*)&bloF[((16 * 4 + q) * 64 + rl16) * 8];
            a0 = MFMA(Ax.v, Bh[16], a0);
            a2 = MFMA(Ax.v, bl_,    a2);
            a4 = MFMA(Lx.v, Bh[16], a4);
        }
        f32x4 D = (a0 + a1) + (a2 + a3) + (a4 + a5);

        // epilogue: lane holds gate row n for batches m=q*4+r.
        // pack (hi,lo)x4 units into one 16B packet per r, tag d0 & d3.
        char* dstB = hx + (size_t)((((t + 1) & 1) * 4 + g) * 128 + wg) * 256;
        const uint_t tag32 = ((uint_t)((t >> 1) & 1)) << 16;
        float pr[4];
        #pragma unroll
        for (int r = 0; r < 4; r++) {
            float v   = D[r] + bias;
            float act = act_gate(v, gtn == 2);
            float v4  = __shfl_xor(act, 4);
            float v8  = __shfl_xor(act, 8);
            float v12 = __shfl_xor(v4, 8);
            // gate G lives at arr[gtn ^ G]; arr = {act, v4, v8, v12}
            float iv = sel4(gtn,     act, v4, v8, v12);
            float fv = sel4(gtn ^ 1, act, v4, v8, v12);
            float gv = sel4(gtn ^ 2, act, v4, v8, v12);
            float ov = sel4(gtn ^ 3, act, v4, v8, v12);
            float cc = fv * cst[r] + iv * gv;
            cst[r] = cc;
            float th = act_gate(cc, 1);
            float h  = ov * th;
            pr[r] = cw * h;
            ushort_t hb = f2bf(h);
            uint_t hvp = (uint_t)hb;
            uint_t lvp = (uint_t)f2bf(h - bf2f(hb));
            uint_t ivp = hvp | (lvp << 16);                 // (hi,lo) unit u
            uint_t ip1 = (uint_t)__shfl_xor((int)ivp, 1);   // unit u^1
            uint_t bl2 = (uint_t)__shfl_xor((int)ivp, 2);   // unit u^2
            uint_t bh2 = (uint_t)__shfl_xor((int)ip1, 2);   // unit u^3
            if (n == 0) {
                u32x4 pkt;
                pkt[0] = (ivp & ~0x10000u) | tag32;
                pkt[1] = ip1;
                pkt[2] = bl2;
                pkt[3] = (bh2 & ~0x10000u) | tag32;
                cst16(dstB + (q * 4 + r) * 16, pkt);
            }
        }
        // NO drain, NO flag: tagged data IS the publication.

        // projection partial (off critical path)
        #pragma unroll
        for (int r = 0; r < 4; r++) {
            pr[r] += __shfl_xor(pr[r], 1);
            pr[r] += __shfl_xor(pr[r], 2);
            if (n == 0) projsh[w][q * 4 + r][t & 63] = pr[r];
        }
        if ((t & 63) == 63) {
            __syncthreads();
            float* dpt = part + (size_t)((g * 32 + s) * 16) * 1024 + (t - 63);
            for (int i = tid; i < 1024; i += NTHR) {
                int b = i >> 6, tl = i & 63;
                float v = (projsh[0][b][tl] + projsh[1][b][tl]) +
                          (projsh[2][b][tl] + projsh[3][b][tl]);
                __builtin_nontemporal_store(v, dpt + (size_t)b * 1024 + tl);
            }
            __syncthreads();
        }
    }
}

extern "C" void kernel_launch(void* const* d_in, const int* in_sizes, int n_in,
                              void* d_out, int out_size, void* d_ws, size_t ws_size,
                              hipStream_t stream) {
    const float* in  = (const float*)d_in[0];
    const float* Wih = (const float*)d_in[1];
    const float* Whh = (const float*)d_in[2];
    const float* bih = (const float*)d_in[3];
    const float* bhh = (const float*)d_in[4];
    const float* cvw = (const float*)d_in[5];
    const float* cvb = (const float*)d_in[6];
    float* out = (float*)d_out;

    char* ws = (char*)d_ws;
    ushort_t* wh  = (ushort_t*)ws; ws += (size_t)2048 * KDIM * 2;      // 2,228,224
    ushort_t* wl  = (ushort_t*)ws; ws += (size_t)2048 * KDIM * 2;
    ushort_t* xh  = (ushort_t*)ws; ws += (size_t)1024 * 64 * 32 * 2;   // 4,194,304
    ushort_t* xl  = (ushort_t*)ws; ws += (size_t)1024 * 64 * 32 * 2;
    char*     hx  = ws;            ws += (size_t)2 * 4 * 128 * 16 * 16;// 262,144
    float*    pp  = (float*)ws;    ws += (size_t)128 * 16 * 1024 * 4;  // 8,388,608
    // total ~21.5 MB of ws

    k_init<<<256, 256, 0, stream>>>((uint_t*)hx);
    k_wcat<<<2048, 256, 0, stream>>>(Wih, Whh, wh, wl);
    k_xbuf<<<512, 256, 0, stream>>>(in, xh, xl);
    k_lstm<<<NBLK, NTHR, 0, stream>>>(wh, wl, xh, xl, hx,
                                      bih, bhh, cvw, pp);
    k_reduce<<<256, 256, 0, stream>>>(pp, out, cvb);
}

// Round 13
// 3978.489 us; speedup vs baseline: 1.3205x; 1.0341x over previous
//
#include <hip/hip_runtime.h>
#include <hip/hip_bf16.h>

// LSTM: B=64, D=32, H=512, T=1024. gates = [h,x] @ [W_hh;W_ih]^T + b_ih + b_hh
// Round 13: halve sync fan-in. 64 blocks = 4 groups x 16 slices of 32 units,
// 512 threads (8 waves; per-wave work IDENTICAL to R12: 4 units, 16 gate
// rows, 51 MFMAs). W_hi AND W_lo both in VGPRs (no bloF LDS, ~200 VGPR,
// 2 waves/SIMD). h exchange: R12's validated data-as-flag scheme unchanged
// (16B packets, tag bit16 in d0/d3, tag=(t>>1)&1 ring-2, coherent dwordx4
// sc0 sc1, retry + s_sleep backoff). Producers per group: 16 blocks (was 32)
// -> smaller straggler max; staging ops device-wide halved (64x2048 packets).
// LDS: hs dbuf 64 KB + projsh 16 KB = 80 KB.

typedef unsigned short ushort_t;
typedef unsigned int   uint_t;
typedef unsigned long long u64_t;
typedef __attribute__((ext_vector_type(8))) short bf16x8;
typedef __attribute__((ext_vector_type(4))) float f32x4;
typedef __attribute__((ext_vector_type(4))) uint_t u32x4;

#define T_STEPS 1024
#define HID     512
#define KDIM    544   // 512 h + 32 x
#define NBLK    64    // 4 groups * 16 slices
#define NTHR    512

__device__ inline ushort_t f2bf(float x) {
    __hip_bfloat16 h = __float2bfloat16(x);
    return *(ushort_t*)&h;
}
__device__ inline float bf2f(ushort_t u) {
    __hip_bfloat16 h = *(__hip_bfloat16*)&u;
    return __bfloat162float(h);
}

__device__ inline f32x4 MFMA(bf16x8 a, bf16x8 b, f32x4 c) {
    return __builtin_amdgcn_mfma_f32_16x16x32_bf16(a, b, c, 0, 0, 0);
}

// coherent 16B load/store (L1+L2 bypass, meets at Infinity Cache)
__device__ inline u32x4 cld16(const void* p) {
    u32x4 v;
    asm volatile("global_load_dwordx4 %0, %1, off sc0 sc1"
                 : "=v"(v) : "v"(p) : "memory");
    return v;
}
__device__ inline void cst16(void* p, u32x4 v) {
    asm volatile("global_store_dwordx4 %0, %1, off sc0 sc1"
                 :: "v"(p), "v"(v) : "memory");
}
__device__ inline void waitvm0() {
    asm volatile("s_waitcnt vmcnt(0)" ::: "memory");
}

// is_tanh: tanh(v)=(1-e)/(1+e), e=2^(-2.885*v); sigmoid(v)=1/(1+e), e=2^(-1.4427*v)
__device__ inline float act_gate(float v, int is_tanh) {
    float vc = fminf(fmaxf(v, -43.f), 43.f);
    float kk = is_tanh ? -2.88539008f : -1.44269504f;
    float e  = __builtin_exp2f(vc * kk);
    float num = is_tanh ? (1.f - e) : 1.f;
    return num * __builtin_amdgcn_rcpf(1.f + e);
}

__device__ inline float sel4(int i, float a, float b, float c, float d) {
    return (i == 0) ? a : (i == 1) ? b : (i == 2) ? c : d;
}

// ---------- prep kernels ----------

__global__ void k_init(uint_t* hx32) {
    int i = blockIdx.x * 256 + threadIdx.x;      // grid 256x256 = 65536
    // init h ring: value ~0 (denormal bf16), tag bit16 = 1 (differs from tag 0
    // expected at t=1/t=2) -> no ABA with init data.
    hx32[i] = 0x00010000u;                       // 2*4*128*16 x 16B = 65536 u32
}

__global__ void k_wcat(const float* __restrict__ wih, const float* __restrict__ whh,
                       ushort_t* __restrict__ wh, ushort_t* __restrict__ wl) {
    int r = blockIdx.x;                          // 2048 gate rows
    for (int k = threadIdx.x; k < KDIM; k += 256) {
        float w = (k < 512) ? whh[r * 512 + k] : wih[r * 32 + (k - 512)];
        ushort_t hh = f2bf(w);
        ushort_t ll = f2bf(w - bf2f(hh));
        wh[r * KDIM + k] = hh;
        wl[r * KDIM + k] = ll;
    }
}

// input (B=64, D=32, T=1024) fp32 -> xbuf[t][b][d] bf16 hi/lo
__global__ void k_xbuf(const float* __restrict__ in,
                       ushort_t* __restrict__ xh, ushort_t* __restrict__ xl) {
    __shared__ float tile[64][65];
    int bp = blockIdx.x >> 4;                    // batch pair 0..31
    int tt = blockIdx.x & 15;                    // t tile 0..15
    int t0 = tt * 64;
    int wv = threadIdx.x >> 6, l = threadIdx.x & 63;
    for (int r = wv * 16; r < wv * 16 + 16; r++) {
        int b = bp * 2 + (r >> 5), d = r & 31;
        tile[r][l] = in[(b * 32 + d) * 1024 + t0 + l];
    }
    __syncthreads();
    for (int i = 0; i < 16; i++) {
        int tl = wv * 16 + i;
        float v = tile[l][tl];
        ushort_t hh = f2bf(v);
        ushort_t ll = f2bf(v - bf2f(hh));
        int o = (t0 + tl) * 2048 + bp * 64 + l;  // = t*64*32 + b*32 + d
        xh[o] = hh;
        xl[o] = ll;
    }
}

// out[b][t] = conv_b + sum_s part[(g*16+s)*16 + bl][t]   (b = g*16+bl)
__global__ void k_reduce(const float* __restrict__ part, float* __restrict__ out,
                         const float* __restrict__ cvb) {
    int b = blockIdx.x >> 2;                     // 0..63
    int t = (blockIdx.x & 3) * 256 + threadIdx.x;
    int g = b >> 4, bl = b & 15;
    const float* p = part + ((size_t)(g * 16 * 16 + bl)) * 1024 + t;
    float sum = 0.f;
    #pragma unroll
    for (int s = 0; s < 16; s++) sum += p[(size_t)s * 16 * 1024];
    out[b * 1024 + t] = sum + cvb[0];
}

// ---------- main recurrent kernel ----------

__global__ __launch_bounds__(NTHR, 2) void k_lstm(
    const ushort_t* __restrict__ wh, const ushort_t* __restrict__ wlo,
    const ushort_t* __restrict__ xh, const ushort_t* __restrict__ xl,
    char* hx,
    const float* __restrict__ bih, const float* __restrict__ bhh,
    const float* __restrict__ convw, float* __restrict__ part)
{
    const int tid = threadIdx.x;
    const int w   = tid >> 6;          // wave 0..7 (unit nibble)
    const int l   = tid & 63;
    const int g   = blockIdx.x >> 4;   // batch group 0..3
    const int s   = blockIdx.x & 15;   // hidden slice 0..15 (32 units each)
    const int n   = l & 15;            // B-tile row within wave
    const int q   = l >> 4;            // quad
    const int gtn = n >> 2;            // gate 0..3 (i,f,g,o)
    const int u   = n & 3;             // unit within wave
    const int j   = s * 32 + w * 4 + u;// hidden unit 0..511
    const int row = gtn * HID + j;     // gate row 0..2047
    const int b0  = g * 16;
    const int wg  = s * 8 + w;         // producing-wave id in group, 0..127

    __shared__ u64_t hs[2][4096];              // staged h, dbuf (64 KB)
    __shared__ float projsh[8][16][32];        // projection partials (16 KB)

    // W_hi AND W_lo fragments in registers: 17 K-chunks each
    bf16x8 Bh[17], Bl[17];
    #pragma unroll
    for (int c = 0; c < 17; c++) {
        Bh[c] = *(const bf16x8*)(wh  + row * KDIM + c * 32 + q * 8);
        Bl[c] = *(const bf16x8*)(wlo + row * KDIM + c * 32 + q * 8);
    }

    const float bias = bih[row] + bhh[row];
    const float cw   = convw[j];
    float cst[4] = {0.f, 0.f, 0.f, 0.f};

    // staging mapping: packet p = k*512+tid (k=0..3) -> wg' = p>>4, m = p&15
    // wg' = k*32 + hi5 (hi5 = tid>>4); c = k*4 + (hi5>>3), q = (hi5>>1)&3,
    // d = hi5&1, n = m
    const int m16 = tid & 15;
    const int hi5 = tid >> 4;
    const int sq  = (hi5 >> 1) & 3, sd = hi5 & 1, sc0v = hi5 >> 3;

    __syncthreads();

    union frag { u64_t d[2]; bf16x8 v; };

    for (int t = 0; t < T_STEPS; t++) {
        frag Ax, Lx;
        // x fragment (no recurrence dependence)
        {
            int xo = (t * 64 + b0 + n) * 32 + q * 8;
            Ax.v = *(const bf16x8*)(xh + xo);
            Lx.v = *(const bf16x8*)(xl + xo);
        }

        // ---- stage + poll-on-data: 4 coherent 16B loads, tag bit16 ----
        const char* srcB = hx + (size_t)(((t & 1) * 4 + g)) * 32768 + tid * 16;
        u32x4 hv[4];
        #pragma unroll
        for (int k = 0; k < 4; k++) hv[k] = cld16(srcB + k * 8192);
        waitvm0();
        if (t > 0) {
            const uint_t exp = ((uint_t)(((t - 1) >> 1) & 1)) << 16;
            for (;;) {
                bool ok = true;
                #pragma unroll
                for (int k = 0; k < 4; k++) {
                    if (((hv[k][0] & 0x10000u) != exp) ||
                        ((hv[k][3] & 0x10000u) != exp)) {
                        hv[k] = cld16(srcB + k * 8192);
                        ok = false;
                    }
                }
                if (ok) break;
                __builtin_amdgcn_s_sleep(1);   // backoff: decongest fabric
                waitvm0();
            }
        }
        // deinterleave dwords (hi,lo)x4 units -> hi x4, lo x4; into LDS dbuf
        {
            const int buf = t & 1;
            #pragma unroll
            for (int k = 0; k < 4; k++) {
                uint_t I0 = hv[k][0], I1 = hv[k][1];
                uint_t I2 = hv[k][2], I3 = hv[k][3];
                uint_t hA = __builtin_amdgcn_perm(I1, I0, 0x05040100u);
                uint_t hB = __builtin_amdgcn_perm(I3, I2, 0x05040100u);
                uint_t lA = __builtin_amdgcn_perm(I1, I0, 0x07060302u);
                uint_t lB = __builtin_amdgcn_perm(I3, I2, 0x07060302u);
                int c  = k * 4 + sc0v;
                int li = ((c * 4 + sq) * 16 + m16) * 2 + sd;
                hs[buf][li]        = (u64_t)hA | ((u64_t)hB << 32);
                hs[buf][li + 2048] = (u64_t)lA | ((u64_t)lB << 32);
            }
        }
        __syncthreads();   // the only per-step barrier

        // fragments from LDS: contiguous 16B b128 reads; B operands in VGPRs
        const int buf = t & 1;
        f32x4 a0 = {0,0,0,0}, a1 = {0,0,0,0}, a2 = {0,0,0,0},
              a3 = {0,0,0,0}, a4 = {0,0,0,0}, a5 = {0,0,0,0};
        #pragma unroll
        for (int c = 0; c < 16; c++) {
            frag Ah, Al;
            int li = ((c * 4 + q) * 16 + n) * 2;
            Ah.v = *(const bf16x8*)&hs[buf][li];
            Al.v = *(const bf16x8*)&hs[buf][li + 2048];
            if (c & 1) {
                a1 = MFMA(Ah.v, Bh[c], a1);
                a3 = MFMA(Ah.v, Bl[c], a3);
                a5 = MFMA(Al.v, Bh[c], a5);
            } else {
                a0 = MFMA(Ah.v, Bh[c], a0);
                a2 = MFMA(Ah.v, Bl[c], a2);
                a4 = MFMA(Al.v, Bh[c], a4);
            }
        }
        {   // x chunk (c=16)
            a0 = MFMA(Ax.v, Bh[16], a0);
            a2 = MFMA(Ax.v, Bl[16], a2);
            a4 = MFMA(Lx.v, Bh[16], a4);
        }
        f32x4 D = (a0 + a1) + (a2 + a3) + (a4 + a5);

        // epilogue: lane holds gate row n for batches m=q*4+r.
        // pack (hi,lo)x4 units into one 16B packet per r, tag d0 & d3.
        char* dstB = hx + (size_t)((((t + 1) & 1) * 4 + g) * 128 + wg) * 256;
        const uint_t tag32 = ((uint_t)((t >> 1) & 1)) << 16;
        float pr[4];
        #pragma unroll
        for (int r = 0; r < 4; r++) {
            float v   = D[r] + bias;
            float act = act_gate(v, gtn == 2);
            float v4  = __shfl_xor(act, 4);
            float v8  = __shfl_xor(act, 8);
            float v12 = __shfl_xor(v4, 8);
            // gate G lives at arr[gtn ^ G]; arr = {act, v4, v8, v12}
            float iv = sel4(gtn,     act, v4, v8, v12);
            float fv = sel4(gtn ^ 1, act, v4, v8, v12);
            float gv = sel4(gtn ^ 2, act, v4, v8, v12);
            float ov = sel4(gtn ^ 3, act, v4, v8, v12);
            float cc = fv * cst[r] + iv * gv;
            cst[r] = cc;
            float th = act_gate(cc, 1);
            float h  = ov * th;
            pr[r] = cw * h;
            ushort_t hb = f2bf(h);
            uint_t hvp = (uint_t)hb;
            uint_t lvp = (uint_t)f2bf(h - bf2f(hb));
            uint_t ivp = hvp | (lvp << 16);                 // (hi,lo) unit u
            uint_t ip1 = (uint_t)__shfl_xor((int)ivp, 1);   // unit u^1
            uint_t bl2 = (uint_t)__shfl_xor((int)ivp, 2);   // unit u^2
            uint_t bh2 = (uint_t)__shfl_xor((int)ip1, 2);   // unit u^3
            if (n == 0) {
                u32x4 pkt;
                pkt[0] = (ivp & ~0x10000u) | tag32;
                pkt[1] = ip1;
                pkt[2] = bl2;
                pkt[3] = (bh2 & ~0x10000u) | tag32;
                cst16(dstB + (q * 4 + r) * 16, pkt);
            }
        }
        // NO drain, NO flag: tagged data IS the publication.

        // projection partial (off critical path)
        #pragma unroll
        for (int r = 0; r < 4; r++) {
            pr[r] += __shfl_xor(pr[r], 1);
            pr[r] += __shfl_xor(pr[r], 2);
            if (n == 0) projsh[w][q * 4 + r][t & 31] = pr[r];
        }
        if ((t & 31) == 31) {
            __syncthreads();
            // 512 entries (16 batches x 32 steps), one per thread
            int b = tid >> 5, tl = tid & 31;
            float v = ((projsh[0][b][tl] + projsh[1][b][tl]) +
                       (projsh[2][b][tl] + projsh[3][b][tl])) +
                      ((projsh[4][b][tl] + projsh[5][b][tl]) +
                       (projsh[6][b][tl] + projsh[7][b][tl]));
            float* dpt = part + (size_t)((g * 16 + s) * 16 + b) * 1024 + (t - 31);
            __builtin_nontemporal_store(v, dpt + tl);
            __syncthreads();
        }
    }
}

extern "C" void kernel_launch(void* const* d_in, const int* in_sizes, int n_in,
                              void* d_out, int out_size, void* d_ws, size_t ws_size,
                              hipStream_t stream) {
    const float* in  = (const float*)d_in[0];
    const float* Wih = (const float*)d_in[1];
    const float* Whh = (const float*)d_in[2];
    const float* bih = (const float*)d_in[3];
    const float* bhh = (const float*)d_in[4];
    const float* cvw = (const float*)d_in[5];
    const float* cvb = (const float*)d_in[6];
    float* out = (float*)d_out;

    char* ws = (char*)d_ws;
    ushort_t* wh  = (ushort_t*)ws; ws += (size_t)2048 * KDIM * 2;      // 2,228,224
    ushort_t* wl  = (ushort_t*)ws; ws += (size_t)2048 * KDIM * 2;
    ushort_t* xh  = (ushort_t*)ws; ws += (size_t)1024 * 64 * 32 * 2;   // 4,194,304
    ushort_t* xl  = (ushort_t*)ws; ws += (size_t)1024 * 64 * 32 * 2;
    char*     hx  = ws;            ws += (size_t)2 * 4 * 128 * 16 * 16;// 262,144
    float*    pp  = (float*)ws;    ws += (size_t)64 * 16 * 1024 * 4;   // 4,194,304
    // total ~17.3 MB of ws

    k_init<<<256, 256, 0, stream>>>((uint_t*)hx);
    k_wcat<<<2048, 256, 0, stream>>>(Wih, Whh, wh, wl);
    k_xbuf<<<512, 256, 0, stream>>>(in, xh, xl);
    k_lstm<<<NBLK, NTHR, 0, stream>>>(wh, wl, xh, xl, hx,
                                      bih, bhh, cvw, pp);
    k_reduce<<<256, 256, 0, stream>>>(pp, out, cvb);
}